// Round 2
// baseline (898.341 us; speedup 1.0000x reference)
//
#include <hip/hip_runtime.h>

#define Hh 51
#define TT 512     // time steps
#define BT 512     // threads per block (8 waves)
#define NB 256     // blocks (2 batch rows each -> 512 rows)

#define LOG2E 1.4426950408889634f

typedef float v2f __attribute__((ext_vector_type(2)));

__device__ __forceinline__ float fexp2(float x) { return __builtin_amdgcn_exp2f(x); }
__device__ __forceinline__ float frcp(float x)  { return __builtin_amdgcn_rcpf(x); }
__device__ __forceinline__ float sigm(float x)  { return frcp(1.f + fexp2(-LOG2E * x)); }
__device__ __forceinline__ float ftanh(float x) { return 1.f - 2.f * frcp(1.f + fexp2(2.f * LOG2E * x)); }

// broadcast lane l of v into an SGPR-resident float (uniform)
__device__ __forceinline__ float rlane(float v, int l) {
    return __int_as_float(__builtin_amdgcn_readlane(__float_as_int(v), l));
}
// acc (VGPR pair) += w (VGPR pair) * h (SGPR pair, wave-uniform)
__device__ __forceinline__ void pkfma(v2f& acc, v2f w, v2f h) {
    asm("v_pk_fma_f32 %0, %1, %2, %0" : "+v"(acc) : "v"(w), "s"(h));
}

__global__ __launch_bounds__(BT, 2) void lstm2_persistent(
    const float* __restrict__ input,   // [512,512]
    const float* __restrict__ W_ih1,   // [204]
    const float* __restrict__ W_hh1,   // [204,51]
    const float* __restrict__ b_ih1,   // [204]
    const float* __restrict__ b_hh1,   // [204]
    const float* __restrict__ W_ih2,   // [204,51]
    const float* __restrict__ W_hh2,   // [204,51]
    const float* __restrict__ b_ih2,   // [204]
    const float* __restrict__ b_hh2,   // [204]
    const float* __restrict__ W_lin,   // [51]
    const float* __restrict__ b_lin,   // [1]
    float* __restrict__ out)           // [512,512]
{
    __shared__ float xbuf[2][TT];          // 4 KB
    __shared__ float h1buf[2][64];         // lane-indexed h vectors (entries >=52 unused)
    __shared__ float h2buf[2][64];
    __shared__ float z1buf[2][256];
    __shared__ float z2buf[2][256];

    const int tid  = threadIdx.x;
    const int row  = tid >> 8;             // 0..1 local batch row
    const int j    = tid & 255;            // gate-row, active < 204
    const int lane = tid & 63;             // lane within wave
    const bool act = (j < 4 * Hh);
    const bool upd = (j < Hh);
    const int grow = (blockIdx.x << 1) + row;

    // preload the 2 input rows (coalesced)
    xbuf[0][tid & 511] = input[((blockIdx.x << 1) + 0) * TT + (tid & 511)];
    xbuf[1][tid & 511] = input[((blockIdx.x << 1) + 1) * TT + (tid & 511)];
    if (tid < 128) { ((float*)h1buf)[tid] = 0.f; ((float*)h2buf)[tid] = 0.f; }

    // persistent weights: 26 k-pairs per matrix per lane (one gate-row j each)
    v2f w1[26], w2[26], w3[26];            // W_hh1, W_ih2, W_hh2 rows
    float wih1 = 0.f, bb1 = 0.f, bb2 = 0.f, wlin = 0.f;
    if (act) {
#pragma unroll
        for (int m = 0; m < 26; ++m) {
            int k0 = 2 * m, k1 = 2 * m + 1;
            float a1v = W_hh1[j * Hh + k0];
            float b1v = (k1 < Hh) ? W_hh1[j * Hh + k1] : 0.f;
            float a2v = W_ih2[j * Hh + k0];
            float b2v = (k1 < Hh) ? W_ih2[j * Hh + k1] : 0.f;
            float a3v = W_hh2[j * Hh + k0];
            float b3v = (k1 < Hh) ? W_hh2[j * Hh + k1] : 0.f;
            w1[m] = (v2f){a1v, b1v};
            w2[m] = (v2f){a2v, b2v};
            w3[m] = (v2f){a3v, b3v};
        }
        wih1 = W_ih1[j];
        bb1  = b_ih1[j] + b_hh1[j];
        bb2  = b_ih2[j] + b_hh2[j];
    } else {
#pragma unroll
        for (int m = 0; m < 26; ++m) {
            w1[m] = (v2f){0.f, 0.f}; w2[m] = (v2f){0.f, 0.f}; w3[m] = (v2f){0.f, 0.f};
        }
    }
    if (upd) wlin = W_lin[j];
    const float blin = b_lin[0];
    float c1 = 0.f, c2 = 0.f;

    __syncthreads();

    for (int t = 0; t < TT; ++t) {
        // ---- phase 1: z1 = b1 + x*Wih1 + Whh1.h1_old ; z2_partial = b2 + Whh2.h2_old
        float vh1 = h1buf[row][lane];      // lane k holds h1_old[k] (wave-local copy)
        float vh2 = h2buf[row][lane];
        float x   = xbuf[row][t];
        v2f a1 = (v2f){bb1, 0.f};
        v2f a2 = (v2f){bb2, 0.f};
#pragma unroll
        for (int m = 0; m < 26; ++m) {
            v2f h1p = (v2f){ rlane(vh1, 2 * m), rlane(vh1, 2 * m + 1) };
            pkfma(a1, w1[m], h1p);
            v2f h2p = (v2f){ rlane(vh2, 2 * m), rlane(vh2, 2 * m + 1) };
            pkfma(a2, w3[m], h2p);
        }
        z1buf[row][j] = fmaf(x, wih1, a1.x + a1.y);
        __syncthreads();                                   // A

        // ---- phase 2: layer-1 gate update (lanes j<51)
        if (upd) {
            float zi = z1buf[row][j];
            float zf = z1buf[row][j + Hh];
            float zg = z1buf[row][j + 2 * Hh];
            float zo = z1buf[row][j + 3 * Hh];
            float ii = sigm(zi), ff = sigm(zf), gg = ftanh(zg), oo = sigm(zo);
            c1 = fmaf(ff, c1, ii * gg);
            h1buf[row][j] = oo * ftanh(c1);
        }
        __syncthreads();                                   // B

        // ---- phase 3: z2 += Wih2.h1_new
        float vh1n = h1buf[row][lane];
#pragma unroll
        for (int m = 0; m < 26; ++m) {
            v2f hp = (v2f){ rlane(vh1n, 2 * m), rlane(vh1n, 2 * m + 1) };
            pkfma(a2, w2[m], hp);
        }
        z2buf[row][j] = a2.x + a2.y;
        __syncthreads();                                   // C

        // ---- phase 4: layer-2 gate update + linear output
        float p = 0.f;
        if (upd) {
            float zi = z2buf[row][j];
            float zf = z2buf[row][j + Hh];
            float zg = z2buf[row][j + 2 * Hh];
            float zo = z2buf[row][j + 3 * Hh];
            float ii = sigm(zi), ff = sigm(zf), gg = ftanh(zg), oo = sigm(zo);
            c2 = fmaf(ff, c2, ii * gg);
            float h2n = oo * ftanh(c2);
            h2buf[row][j] = h2n;
            p = wlin * h2n;
        }
        if ((j >> 6) == 0) {               // wave-uniform: the wave holding lanes j<64
#pragma unroll
            for (int off = 32; off >= 1; off >>= 1)
                p += __shfl_xor(p, off, 64);
            if (j == 0) out[grow * TT + t] = p + blin;
        }
        __syncthreads();                                   // D
    }
}

extern "C" void kernel_launch(void* const* d_in, const int* in_sizes, int n_in,
                              void* d_out, int out_size, void* d_ws, size_t ws_size,
                              hipStream_t stream) {
    const float* input = (const float*)d_in[0];
    const float* W_ih1 = (const float*)d_in[1];
    const float* W_hh1 = (const float*)d_in[2];
    const float* b_ih1 = (const float*)d_in[3];
    const float* b_hh1 = (const float*)d_in[4];
    const float* W_ih2 = (const float*)d_in[5];
    const float* W_hh2 = (const float*)d_in[6];
    const float* b_ih2 = (const float*)d_in[7];
    const float* b_hh2 = (const float*)d_in[8];
    const float* W_lin = (const float*)d_in[9];
    const float* b_lin = (const float*)d_in[10];
    float* out = (float*)d_out;

    hipLaunchKernelGGL(lstm2_persistent, dim3(NB), dim3(BT), 0, stream,
                       input, W_ih1, W_hh1, b_ih1, b_hh1,
                       W_ih2, W_hh2, b_ih2, b_hh2, W_lin, b_lin, out);
}

// Round 3
// 857.451 us; speedup vs baseline: 1.0477x; 1.0477x over previous
//
#include <hip/hip_runtime.h>

#define Hh 51
#define TT 512
#define LOG2E 1.4426950408889634f

typedef float v2f __attribute__((ext_vector_type(2)));

__device__ __forceinline__ float fexp2(float x){ return __builtin_amdgcn_exp2f(x); }
__device__ __forceinline__ float frcp(float x){ return __builtin_amdgcn_rcpf(x); }
__device__ __forceinline__ float sigm(float x){ return frcp(1.f + fexp2(-LOG2E*x)); }
__device__ __forceinline__ float ftanh(float x){ return 1.f - 2.f*frcp(1.f + fexp2(2.f*LOG2E*x)); }
// wave-uniform broadcast of lane l (compile-time l) into SGPR
__device__ __forceinline__ float rlane(float v, int l){
    return __int_as_float(__builtin_amdgcn_readlane(__float_as_int(v), l));
}
// acc (VGPR pair) += w (VGPR pair) * h (wave-uniform SGPR pair)
__device__ __forceinline__ void pkfma(v2f& acc, v2f w, v2f h){
    asm("v_pk_fma_f32 %0, %1, %2, %0" : "+v"(acc) : "v"(w), "s"(h));
}

__global__ __launch_bounds__(256, 2) void lstm2_wavesync(
    const float* __restrict__ input,   // [512,512]
    const float* __restrict__ W_ih1,   // [204]
    const float* __restrict__ W_hh1,   // [204,51]
    const float* __restrict__ b_ih1,
    const float* __restrict__ b_hh1,
    const float* __restrict__ W_ih2,   // [204,51]
    const float* __restrict__ W_hh2,   // [204,51]
    const float* __restrict__ b_ih2,
    const float* __restrict__ b_hh2,
    const float* __restrict__ W_lin,   // [51]
    const float* __restrict__ b_lin,   // [1]
    float* __restrict__ out)           // [512,512]
{
    __shared__ float xbuf[TT];         // this row's input series
    __shared__ float z1buf[256];       // gate pre-activations, slots 204..255 stay 0
    __shared__ float z2buf[256];
    __shared__ float outbuf[TT];       // per-step outputs, flushed at the end

    const int tid = threadIdx.x;
    const int wv  = tid >> 6;          // wave = gate index 0..3 (i,f,g,o)
    const int l   = tid & 63;          // lane = hidden index
    const bool act = (l < Hh);
    const int j   = wv * Hh + l;       // gate-row 0..203 (valid when act)
    const int row = blockIdx.x;        // one batch row per block

    xbuf[tid]       = input[row * TT + tid];
    xbuf[tid + 256] = input[row * TT + tid + 256];
    z1buf[tid] = 0.f;                  // zero incl. pad slots so idle lanes stay finite
    z2buf[tid] = 0.f;

    // persistent weights: one gate-row of W_hh1 / W_ih2 / W_hh2 per lane, k-paired
    v2f w1[26], w2[26], w3[26];
    float wih1 = 0.f, bb1 = 0.f, bb2 = 0.f;
    if (act) {
        const float* r1 = W_hh1 + j * Hh;
        const float* r2 = W_ih2 + j * Hh;
        const float* r3 = W_hh2 + j * Hh;
#pragma unroll
        for (int m = 0; m < 25; ++m) {
            w1[m] = (v2f){r1[2*m], r1[2*m+1]};
            w2[m] = (v2f){r2[2*m], r2[2*m+1]};
            w3[m] = (v2f){r3[2*m], r3[2*m+1]};
        }
        w1[25] = (v2f){r1[50], 0.f};
        w2[25] = (v2f){r2[50], 0.f};
        w3[25] = (v2f){r3[50], 0.f};
        wih1 = W_ih1[j];
        bb1  = b_ih1[j] + b_hh1[j];
        bb2  = b_ih2[j] + b_hh2[j];
    } else {
#pragma unroll
        for (int m = 0; m < 26; ++m) {
            w1[m] = (v2f){0.f,0.f}; w2[m] = (v2f){0.f,0.f}; w3[m] = (v2f){0.f,0.f};
        }
    }
    const float wlin = act ? W_lin[l] : 0.f;
    const float blin = b_lin[0];

    // h/c state: lane l holds index l, replicated (identically) in all 4 waves
    float h1 = 0.f, h2 = 0.f, c1 = 0.f, c2 = 0.f;
    __syncthreads();

    for (int t = 0; t < TT; ++t) {
        // ---- phase 1: z1[j] = bb1 + x*wih1 + Whh1[j,:]·h1 ; a2 = bb2 + Whh2[j,:]·h2
        float x = xbuf[t];
        v2f a1 = (v2f){fmaf(x, wih1, bb1), 0.f};
        v2f a2 = (v2f){bb2, 0.f};
#pragma unroll
        for (int m = 0; m < 26; ++m) {
            v2f hp1 = (v2f){ rlane(h1, 2*m), rlane(h1, 2*m+1) };
            pkfma(a1, w1[m], hp1);
            v2f hp2 = (v2f){ rlane(h2, 2*m), rlane(h2, 2*m+1) };
            pkfma(a2, w3[m], hp2);
        }
        if (act) z1buf[j] = a1.x + a1.y;
        __syncthreads();                                   // barrier 1: z1 exchange

        // ---- phase 2: layer-1 update, redundantly in all 4 waves (h1,c1 per-lane regs)
        {
            float zi = z1buf[l];
            float zf = z1buf[Hh + l];
            float zg = z1buf[2*Hh + l];
            float zo = z1buf[3*Hh + l];
            float ii = sigm(zi), ff = sigm(zf), gg = ftanh(zg), oo = sigm(zo);
            c1 = fmaf(ff, c1, ii * gg);
            h1 = oo * ftanh(c1);
        }

        // ---- phase 3: a2 += Wih2[j,:]·h1_new (h1_new is in this wave's own lanes)
#pragma unroll
        for (int m = 0; m < 26; ++m) {
            v2f hp = (v2f){ rlane(h1, 2*m), rlane(h1, 2*m+1) };
            pkfma(a2, w2[m], hp);
        }
        if (act) z2buf[j] = a2.x + a2.y;
        __syncthreads();                                   // barrier 2: z2 exchange

        // ---- phase 4: layer-2 update, redundant in all waves
        {
            float zi = z2buf[l];
            float zf = z2buf[Hh + l];
            float zg = z2buf[2*Hh + l];
            float zo = z2buf[3*Hh + l];
            float ii = sigm(zi), ff = sigm(zf), gg = ftanh(zg), oo = sigm(zo);
            c2 = fmaf(ff, c2, ii * gg);
            h2 = oo * ftanh(c2);
        }

        // ---- output: wave 0 reduces Wlin·h2 into the LDS out buffer
        if (wv == 0) {
            float p = wlin * h2;
#pragma unroll
            for (int off = 32; off >= 1; off >>= 1)
                p += __shfl_xor(p, off, 64);
            if (l == 0) outbuf[t] = p + blin;
        }
    }
    __syncthreads();
    out[row * TT + tid]       = outbuf[tid];
    out[row * TT + tid + 256] = outbuf[tid + 256];
}

extern "C" void kernel_launch(void* const* d_in, const int* in_sizes, int n_in,
                              void* d_out, int out_size, void* d_ws, size_t ws_size,
                              hipStream_t stream) {
    const float* input = (const float*)d_in[0];
    const float* W_ih1 = (const float*)d_in[1];
    const float* W_hh1 = (const float*)d_in[2];
    const float* b_ih1 = (const float*)d_in[3];
    const float* b_hh1 = (const float*)d_in[4];
    const float* W_ih2 = (const float*)d_in[5];
    const float* W_hh2 = (const float*)d_in[6];
    const float* b_ih2 = (const float*)d_in[7];
    const float* b_hh2 = (const float*)d_in[8];
    const float* W_lin = (const float*)d_in[9];
    const float* b_lin = (const float*)d_in[10];
    float* out = (float*)d_out;

    hipLaunchKernelGGL(lstm2_wavesync, dim3(512), dim3(256), 0, stream,
                       input, W_ih1, W_hh1, b_ih1, b_hh1,
                       W_ih2, W_hh2, b_ih2, b_hh2, W_lin, b_lin, out);
}